// Round 14
// baseline (56.205 us; speedup 1.0000x reference)
//
#include <hip/hip_runtime.h>
#include <hip/hip_bf16.h>
#include <math.h>

#define COUPLING 0.12f
#define EPSV 1e-8f
#define SCALE2L2E 2.8853900817779268f   // 2*log2(e): folds tanh's 2x and exp->exp2

typedef __attribute__((ext_vector_type(8))) short bf16x8;
typedef __attribute__((ext_vector_type(4))) float f32x4;

// tanh(x) from y = 2x*log2(e):  tanh = 1 - 2/(1+2^y). Inf-safe both ways.
__device__ __forceinline__ float tanh_from_e2(float y) {
    float e = __builtin_amdgcn_exp2f(y);
    float r = __builtin_amdgcn_rcpf(1.0f + e);
    return fmaf(-2.0f, r, 1.0f);
}
__device__ __forceinline__ float tanh_fast(float x) {
    return tanh_from_e2(SCALE2L2E * x);
}
// sigma(y) = 1/(1+2^y); tanh = 1 - 2*sigma.
__device__ __forceinline__ float sig_e2(float y) {
    float e = __builtin_amdgcn_exp2f(y);
    return __builtin_amdgcn_rcpf(1.0f + e);
}

__device__ __forceinline__ short f2bf(float f) {
    __hip_bfloat16 h = __float2bfloat16(f);
    return __builtin_bit_cast(short, h);
}

// Main, round-17: CACHE-SERVED TILES, ZERO LOOP SYNC.
// 13 rounds of evidence: the LDS phase pipeline's residuals are ~6us/pass
// of barrier/sync overhead (warm 17us vs 11us VALU floor, R9) + ~12us cold
// memory exposure, and every occupancy attempt on that structure failed
// because it couples LDS size + VGPR + residency (R8/R10/R12/R13, four
// different confounders). Root fix per Common-mistake #7: the only reason
// for LDS staging was sharing each 2KB tile among 4 waves -- but L1/L2
// serve that 4x redundancy trivially (268MB L2 traffic over ~15us = 70GB/s
// /CU << L2 share; HBM-unique stays 67MB). So: DROP LDS staging entirely.
// Each wave = independent depth-2 register pipeline (R0's proven direct
// per-lane fragment load: lane (col,kg) reads z_past[t*16+col][kg*8..+8],
// a 2KB-contiguous fully-coalesced wave access) running R11's proven
// 2-group MFMA/sigma core. Removes: all barriers, lgkm waits, ds ops,
// swizzle, ring, and 16 VGPRs of pipeline pre-sets. Live set ~40-48 VGPR
// (R11's measured 44 - 16 presets + 8 rolling-next) -> 8 blocks/CU at
// nblk=2048 by ACTUAL usage ((256,4) caps 128, no clamp risk); ~32MB of
// loads in flight chip-wide >> 5.7MB Little's-law need.
// C/D layout: col=lane&15, row=(lane>>4)*4+reg (m89-verified).
__global__ __launch_bounds__(256, 4) void phot_main(
    const float* __restrict__ z_past,   // [P][32] fp32
    const float* __restrict__ heads_w,  // [128][64]
    const float* __restrict__ heads_b,  // [128]
    const float* __restrict__ cand,     // [32]
    float* __restrict__ partials,       // [NB][128]
    int P, int NB)                      // NB = grid size
{
    __shared__ float wacc[128];
    __shared__ float cpre_l[128];

    const int tid  = threadIdx.x;
    const int lane = tid & 63;
    const int wv   = tid >> 6;
    const int col  = lane & 15;   // A-row / B-col / C-col
    const int kg   = lane >> 4;   // k-group (k = kg*8 + e)

    // ---- prep: cpre into LDS (one barrier, outside the loop) ----
    if (tid < 128) {
        const float* wr = heads_w + (size_t)tid * 64;
        float s0 = heads_b[tid], s1 = 0.f, s2 = 0.f, s3 = 0.f;
        #pragma unroll
        for (int k = 0; k < 32; k += 4) {
            s0 = fmaf(wr[k+0], cand[k+0], s0);
            s1 = fmaf(wr[k+1], cand[k+1], s1);
            s2 = fmaf(wr[k+2], cand[k+2], s2);
            s3 = fmaf(wr[k+3], cand[k+3], s3);
        }
        cpre_l[tid] = SCALE2L2E * ((s0 + s1) + (s2 + s3));
    }

    // This wave's 2 channel groups: B-fragments built in registers from
    // L2-resident heads_w (single-use -> no LDS needed).
    const int g0 = wv * 2, g1 = g0 + 1;
    bf16x8 bfA, bfB;
    {
        const float* wA = heads_w + (size_t)(g0 * 16 + col) * 64 + 32 + kg * 8;
        const float* wB = heads_w + (size_t)(g1 * 16 + col) * 64 + 32 + kg * 8;
        f32x4 a0 = *(const f32x4*)wA, a1 = *(const f32x4*)(wA + 4);
        f32x4 b0 = *(const f32x4*)wB, b1 = *(const f32x4*)(wB + 4);
        bfA[0]=f2bf(SCALE2L2E*a0[0]); bfA[1]=f2bf(SCALE2L2E*a0[1]);
        bfA[2]=f2bf(SCALE2L2E*a0[2]); bfA[3]=f2bf(SCALE2L2E*a0[3]);
        bfA[4]=f2bf(SCALE2L2E*a1[0]); bfA[5]=f2bf(SCALE2L2E*a1[1]);
        bfA[6]=f2bf(SCALE2L2E*a1[2]); bfA[7]=f2bf(SCALE2L2E*a1[3]);
        bfB[0]=f2bf(SCALE2L2E*b0[0]); bfB[1]=f2bf(SCALE2L2E*b0[1]);
        bfB[2]=f2bf(SCALE2L2E*b0[2]); bfB[3]=f2bf(SCALE2L2E*b0[3]);
        bfB[4]=f2bf(SCALE2L2E*b1[0]); bfB[5]=f2bf(SCALE2L2E*b1[1]);
        bfB[6]=f2bf(SCALE2L2E*b1[2]); bfB[7]=f2bf(SCALE2L2E*b1[3]);
    }
    __syncthreads();
    const float cpA = cpre_l[g0 * 16 + col];
    const float cpB = cpre_l[g1 * 16 + col];
    const f32x4 cvA = {cpA, cpA, cpA, cpA};
    const f32x4 cvB = {cpB, cpB, cpB, cpB};

    f32x4 accA = {0,0,0,0}, accB = {0,0,0,0};

    const int T  = (P + 15) >> 4;             // total 16-row tiles
    const int Tf = P >> 4;                    // full tiles
    const int b  = blockIdx.x;
    const int K  = (b < T) ? ((T - 1 - b) / NB + 1) : 0;   // tiles for this block

    // Per-lane direct fragment address component: row = t*16 + col.
    const bool uni = ((T % NB) == 0) && (Tf == T);   // uniform shape fast path

    if (K > 0) {
        if (uni) {
            // Depth-2 register pipeline, no clamps, no guards, no barriers.
            int row = b * 16 + col;
            const float* g = z_past + (size_t)row * 32 + kg * 8;
            f32x4 cl = *(const f32x4*)g;
            f32x4 ch = *(const f32x4*)(g + 4);
            const size_t step = (size_t)NB * 16 * 32;   // floats per tile stride
            for (int k = 0; k < K; ++k) {
                f32x4 nl, nh;
                if (k + 1 < K) {
                    const float* gn = g + (size_t)(k + 1) * step;
                    nl = *(const f32x4*)gn;
                    nh = *(const f32x4*)(gn + 4);
                }
                bf16x8 a;
                a[0]=f2bf(cl[0]); a[1]=f2bf(cl[1]); a[2]=f2bf(cl[2]); a[3]=f2bf(cl[3]);
                a[4]=f2bf(ch[0]); a[5]=f2bf(ch[1]); a[6]=f2bf(ch[2]); a[7]=f2bf(ch[3]);
                f32x4 d = __builtin_amdgcn_mfma_f32_16x16x32_bf16(a, bfA, cvA, 0, 0, 0);
                accA[0] += sig_e2(d[0]); accA[1] += sig_e2(d[1]);
                accA[2] += sig_e2(d[2]); accA[3] += sig_e2(d[3]);
                d = __builtin_amdgcn_mfma_f32_16x16x32_bf16(a, bfB, cvB, 0, 0, 0);
                accB[0] += sig_e2(d[0]); accB[1] += sig_e2(d[1]);
                accB[2] += sig_e2(d[2]); accB[3] += sig_e2(d[3]);
                cl = nl; ch = nh;
            }
        } else {
            // General path: clamped loads + per-element guards (R0-proven).
            for (int k = 0; k < K; ++k) {
                const int t = b + k * NB;
                int row = t * 16 + col; if (row > P - 1) row = P - 1;
                const float* g = z_past + (size_t)row * 32 + kg * 8;
                f32x4 cl = *(const f32x4*)g;
                f32x4 ch = *(const f32x4*)(g + 4);
                bf16x8 a;
                a[0]=f2bf(cl[0]); a[1]=f2bf(cl[1]); a[2]=f2bf(cl[2]); a[3]=f2bf(cl[3]);
                a[4]=f2bf(ch[0]); a[5]=f2bf(ch[1]); a[6]=f2bf(ch[2]); a[7]=f2bf(ch[3]);
                const int base = t * 16;
                if (base + 16 <= P) {
                    f32x4 d = __builtin_amdgcn_mfma_f32_16x16x32_bf16(a, bfA, cvA, 0, 0, 0);
                    accA[0] += sig_e2(d[0]); accA[1] += sig_e2(d[1]);
                    accA[2] += sig_e2(d[2]); accA[3] += sig_e2(d[3]);
                    d = __builtin_amdgcn_mfma_f32_16x16x32_bf16(a, bfB, cvB, 0, 0, 0);
                    accB[0] += sig_e2(d[0]); accB[1] += sig_e2(d[1]);
                    accB[2] += sig_e2(d[2]); accB[3] += sig_e2(d[3]);
                } else {
                    const int r0 = base + kg * 4;
                    f32x4 d = __builtin_amdgcn_mfma_f32_16x16x32_bf16(a, bfA, cvA, 0, 0, 0);
                    if (r0 + 0 < P) accA[0] += sig_e2(d[0]);
                    if (r0 + 1 < P) accA[1] += sig_e2(d[1]);
                    if (r0 + 2 < P) accA[2] += sig_e2(d[2]);
                    if (r0 + 3 < P) accA[3] += sig_e2(d[3]);
                    d = __builtin_amdgcn_mfma_f32_16x16x32_bf16(a, bfB, cvB, 0, 0, 0);
                    if (r0 + 0 < P) accB[0] += sig_e2(d[0]);
                    if (r0 + 1 < P) accB[1] += sig_e2(d[1]);
                    if (r0 + 2 < P) accB[2] += sig_e2(d[2]);
                    if (r0 + 3 < P) accB[3] += sig_e2(d[3]);
                }
            }
        }
    }

    // Per-lane valid-row count (analytic).
    float nsum = 0.0f;
    if (K > 0) {
        int nfull = (b < Tf) ? ((Tf - 1 - b) / NB + 1) : 0;
        nsum = 4.0f * (float)nfull;
        if (Tf < T && b <= Tf && ((Tf - b) % NB) == 0) {   // block owns partial tile
            int prem = P - Tf * 16;
            int nv = prem - kg * 4; if (nv < 0) nv = 0; if (nv > 4) nv = 4;
            nsum += (float)nv;
        }
    }

    // sum(tanh) = nsum - 2*sum(sigma); fold 4 row-regs, then 4 k-groups.
    float sA = nsum - 2.0f * ((accA[0] + accA[1]) + (accA[2] + accA[3]));
    sA += __shfl_xor(sA, 16, 64);
    sA += __shfl_xor(sA, 32, 64);
    float sB = nsum - 2.0f * ((accB[0] + accB[1]) + (accB[2] + accB[3]));
    sB += __shfl_xor(sB, 16, 64);
    sB += __shfl_xor(sB, 32, 64);
    if (lane < 16) {
        wacc[g0 * 16 + lane] = sA;
        wacc[g1 * 16 + lane] = sB;
    }
    __syncthreads();
    if (tid < 128) {
        partials[(size_t)b * 128 + tid] = wacc[tid];
    }
}

// Finalize: generic 16-deep-ILP partials reduction (256B/lane in flight;
// the cross-XCD read is latency-bound). cnt = nblk/32 = 64 at nblk=2048.
__global__ __launch_bounds__(1024) void phot_finalize(
    const float* __restrict__ partials, int nblk, int P,
    const float* __restrict__ out_w,      // [32][128]
    const float* __restrict__ out_b,      // [32]
    const float* __restrict__ rel_bias,   // [129][2]
    const float* __restrict__ cand,       // [32]
    const float* __restrict__ norm_scale, // [1]
    const int* __restrict__ posp,         // [1]
    float* __restrict__ out)              // [32]
{
    __shared__ __align__(16) float sh[4096];   // [slice 0..31][128 ch]
    __shared__ float  cm[128];
    __shared__ float  outv[32];
    __shared__ double db[512];
    __shared__ float  bm[2];

    const int t   = threadIdx.x;
    const int chg = t & 31;         // channel group (4 channels)
    const int sl  = t >> 5;         // 0..31 slices over blocks

    const int cnt = nblk >> 5;      // nblk is a multiple of 32
    const float* p0 = partials + (size_t)(sl * cnt) * 128 + chg * 4;
    f32x4 s0 = {0,0,0,0}, s1 = {0,0,0,0}, s2 = {0,0,0,0}, s3 = {0,0,0,0};
    int i = 0;
    for (; i + 16 <= cnt; i += 16) {
        f32x4 v[16];
        #pragma unroll
        for (int j = 0; j < 16; ++j)
            v[j] = *(const f32x4*)(p0 + (size_t)(i + j) * 128);
        #pragma unroll
        for (int j = 0; j < 16; j += 4) {
            s0 += v[j+0]; s1 += v[j+1]; s2 += v[j+2]; s3 += v[j+3];
        }
    }
    for (; i < cnt; ++i) s0 += *(const f32x4*)(p0 + (size_t)i * 128);
    f32x4 acc = (s0 + s1) + (s2 + s3);
    *(f32x4*)&sh[sl * 128 + chg * 4] = acc;
    __syncthreads();

    if (t < 128) {
        float s = 0.0f;
        #pragma unroll
        for (int s2i = 0; s2i < 32; ++s2i) s += sh[t + 128 * s2i];
        cm[t] = s / (float)P;
    }

    // rel-bias mean, closed form per bin; idx(p)=clamp(a+p,0,128), a=pos-P+64
    if (t < 512) {
        const int c = t >> 8, j = t & 255;
        double v = 0.0;
        if (j <= 128) {
            const long long pos = (long long)(*posp);
            const long long a = pos - (long long)P + 64;
            double cnt2;
            if (j == 0) {
                long long hi = -a; if (hi > (long long)P - 1) hi = (long long)P - 1;
                cnt2 = (hi >= 0) ? (double)(hi + 1) : 0.0;
            } else if (j == 128) {
                long long lo = 128 - a; if (lo < 0) lo = 0;
                cnt2 = (lo <= (long long)P - 1) ? (double)((long long)P - lo) : 0.0;
            } else {
                long long p = (long long)j - a;
                cnt2 = (p >= 0 && p < (long long)P) ? 1.0 : 0.0;
            }
            v = cnt2 * (double)rel_bias[2*j + c];
        }
        db[t] = v;
    }
    __syncthreads();
    #pragma unroll
    for (int s = 128; s >= 1; s >>= 1) {
        if (t < 512 && (t & 255) < s) db[t] += db[t + s];
        __syncthreads();
    }
    if (t < 2) bm[t] = (float)(db[t << 8] / (double)P);
    __syncthreads();

    if (t < 32) {
        const float* wr = out_w + t * 128;
        float o0 = out_b[t], o1 = 0.f, o2 = 0.f, o3 = 0.f;
        #pragma unroll
        for (int j = 0; j < 128; j += 4) {
            o0 = fmaf(wr[j+0], cm[j+0], o0);
            o1 = fmaf(wr[j+1], cm[j+1], o1);
            o2 = fmaf(wr[j+2], cm[j+2], o2);
            o3 = fmaf(wr[j+3], cm[j+3], o3);
        }
        outv[t] = (o0+o1) + (o2+o3);
    }
    __syncthreads();

    if (t < 32) {
        float zt = tanh_fast(cand[t] + COUPLING * (outv[t] + bm[t & 1]));
        float other = __shfl_xor(zt, 1, 64);
        float m = fmaf(zt, zt, other * other);
        #pragma unroll
        for (int off = 2; off < 32; off <<= 1) m = fmaxf(m, __shfl_xor(m, off, 64));
        float scale = norm_scale[0] / sqrtf(m + EPSV);
        out[t] = (m > 0.0f) ? zt * scale : zt;
    }
}

extern "C" void kernel_launch(void* const* d_in, const int* in_sizes, int n_in,
                              void* d_out, int out_size, void* d_ws, size_t ws_size,
                              hipStream_t stream)
{
    const float* cand       = (const float*)d_in[0];
    const float* z_past     = (const float*)d_in[1];
    const float* heads_w    = (const float*)d_in[2];
    const float* heads_b    = (const float*)d_in[3];
    const float* out_w      = (const float*)d_in[4];
    const float* out_b      = (const float*)d_in[5];
    const float* rel_bias   = (const float*)d_in[6];
    const float* norm_scale = (const float*)d_in[7];
    const int*   posp       = (const int*)d_in[8];

    const int P = in_sizes[1] / 32;

    int nblk = 2048;     // 8 blocks/CU by actual usage: ~40-48 VGPR, ~1KB LDS
    size_t need = (size_t)nblk * 128 * sizeof(float);
    if (need > ws_size) {
        nblk = (int)(ws_size / (128 * sizeof(float)));
        nblk &= ~31;
        if (nblk < 32) nblk = 32;
    }
    float* partials = (float*)d_ws;

    phot_main<<<nblk, 256, 0, stream>>>(z_past, heads_w, heads_b, cand,
                                        partials, P, nblk);
    phot_finalize<<<1, 1024, 0, stream>>>(partials, nblk, P, out_w, out_b,
                                          rel_bias, cand, norm_scale, posp,
                                          (float*)d_out);
}